// Round 1
// baseline (1250.232 us; speedup 1.0000x reference)
//
#include <hip/hip_runtime.h>

// Problem constants
// C=2048, KT=64, D=1024, De=128, Df=256, H=8, dh=128, X=D+De=1152, PH=1024

#define DEV __device__ __forceinline__

typedef __attribute__((ext_vector_type(4))) float f32x4;
typedef __attribute__((ext_vector_type(8))) short bf16x8;
typedef __attribute__((ext_vector_type(4))) unsigned short u16x4;

DEV unsigned short f2b(float f) {
  unsigned int u = __builtin_bit_cast(unsigned int, f);
  u = u + 0x7fffu + ((u >> 16) & 1u);   // round-to-nearest-even
  return (unsigned short)(u >> 16);
}

// ---------------------------------------------------------------------------
// Generic 64x64-tile bf16 MFMA GEMM (M always 2048, rows = c).
// All B operands except MQT are "BT" layout (N rows, K contiguous).
// ---------------------------------------------------------------------------
enum { MQ = 0, MQT = 1, MAP = 2, MG1 = 3, MG2 = 4 };

template <int MODE>
__global__ __launch_bounds__(256) void gemm64(
    const float* __restrict__ A1, const float* __restrict__ A2,
    const unsigned short* __restrict__ Ab,
    const float* __restrict__ B1, const float* __restrict__ B2,
    const float* __restrict__ scale2, const float* __restrict__ bias,
    float* __restrict__ OutF, unsigned short* __restrict__ OutB)
{
  __shared__ unsigned short As[64 * 40];  // 64 rows x 32 k, stride 40 (pad)
  __shared__ unsigned short Bs[64 * 40];

  const int tid = threadIdx.x;
  const int lane = tid & 63, wv = tid >> 6;
  const int l15 = lane & 15, s = lane >> 4;
  const int bx = blockIdx.x, by = blockIdx.y, h = blockIdx.z;
  const int c0 = by * 64;
  const int n0 = bx * 64;

  int K;
  if constexpr (MODE == MQ) K = 1280;        // 1024 (w·W2) + 256 (beta·fC·Wf)
  else if constexpr (MODE == MQT) K = 128;
  else if constexpr (MODE == MAP) K = 1152;
  else if constexpr (MODE == MG1) K = 1152;  // 1024 (w) + 128 (Etmean)
  else K = 1024;

  float s2 = 1.0f;
  if constexpr (MODE == MQ) s2 = scale2[0];  // beta

  f32x4 acc[4] = {};

  for (int k0 = 0; k0 < K; k0 += 32) {
    // ---- stage A tile (64 x 32) ----
    if constexpr (MODE == MQ || MODE == MG1) {
      #pragma unroll
      for (int p = 0; p < 2; ++p) {
        int flat = tid + 256 * p;
        int r = flat >> 3, kc = (flat & 7) * 4;
        int k = k0 + kc;
        float4 v;
        if constexpr (MODE == MQ) {
          if (k < 1024) v = *(const float4*)(A1 + (size_t)(c0 + r) * 1024 + k);
          else {
            v = *(const float4*)(A2 + (size_t)(c0 + r) * 256 + (k - 1024));
            v.x *= s2; v.y *= s2; v.z *= s2; v.w *= s2;
          }
        } else {
          if (k < 1024) v = *(const float4*)(A1 + (size_t)(c0 + r) * 1024 + k);
          else v = *(const float4*)(A2 + (size_t)(c0 + r) * 128 + (k - 1024));
        }
        unsigned short* dst = As + r * 40 + kc;
        dst[0] = f2b(v.x); dst[1] = f2b(v.y); dst[2] = f2b(v.z); dst[3] = f2b(v.w);
      }
    } else {
      // bf16 A source
      int r = tid >> 2, kc = (tid & 3) * 8;
      size_t lda, aoff;
      if constexpr (MODE == MQT)      { lda = 1024; aoff = (size_t)h * 128; }
      else if constexpr (MODE == MAP) { lda = 9216; aoff = (size_t)h * 1152; }
      else                            { lda = 1024; aoff = 0; }
      bf16x8 v = *(const bf16x8*)(Ab + (size_t)(c0 + r) * lda + aoff + k0 + kc);
      *(bf16x8*)(As + r * 40 + kc) = v;
    }
    // ---- stage B tile ----
    if constexpr (MODE == MQT) {
      // W1 slice, BN layout (contraction = row index): transpose into LDS
      #pragma unroll
      for (int p = 0; p < 8; ++p) {
        int flat = tid + 256 * p;
        int kk = flat >> 6, nn = flat & 63;
        float v = B1[(size_t)(h * 128 + k0 + kk) * 1152 + n0 + nn];
        Bs[nn * 40 + kk] = f2b(v);
      }
    } else {
      #pragma unroll
      for (int p = 0; p < 2; ++p) {
        int flat = tid + 256 * p;
        int nn = flat >> 3, kc = (flat & 7) * 4;
        int k = k0 + kc;
        float4 v;
        if constexpr (MODE == MQ) {
          if (k < 1024) v = *(const float4*)(B1 + (size_t)(n0 + nn) * 1024 + k);
          else v = *(const float4*)(B2 + (size_t)(n0 + nn) * 256 + (k - 1024));
        } else if constexpr (MODE == MAP) {
          v = *(const float4*)(B1 + (size_t)(h * 128 + n0 + nn) * 1152 + k);
        } else if constexpr (MODE == MG1) {
          v = *(const float4*)(B1 + (size_t)(n0 + nn) * 1152 + k);
        } else {  // MG2
          v = *(const float4*)(B1 + (size_t)(n0 + nn) * 1024 + k);
        }
        unsigned short* dst = Bs + nn * 40 + kc;
        dst[0] = f2b(v.x); dst[1] = f2b(v.y); dst[2] = f2b(v.z); dst[3] = f2b(v.w);
      }
    }
    __syncthreads();
    // ---- fragments + MFMA (wave wv owns N-sub [wv*16, wv*16+16)) ----
    bf16x8 bF = *(const bf16x8*)(Bs + (wv * 16 + l15) * 40 + s * 8);
    #pragma unroll
    for (int ms = 0; ms < 4; ++ms) {
      bf16x8 aF = *(const bf16x8*)(As + (ms * 16 + l15) * 40 + s * 8);
      acc[ms] = __builtin_amdgcn_mfma_f32_16x16x32_bf16(aF, bF, acc[ms], 0, 0, 0);
    }
    __syncthreads();
  }

  // ---- epilogue: D layout col=lane&15, row=(lane>>4)*4+reg ----
  #pragma unroll
  for (int ms = 0; ms < 4; ++ms) {
    #pragma unroll
    for (int r = 0; r < 4; ++r) {
      int row = c0 + ms * 16 + s * 4 + r;
      int col = n0 + wv * 16 + l15;
      float v = acc[ms][r];
      if constexpr (MODE == MQ) {
        OutB[(size_t)row * 1024 + col] = f2b(v);
      } else if constexpr (MODE == MQT) {
        OutB[(size_t)row * 9216 + h * 1152 + col] = f2b(v);
      } else if constexpr (MODE == MAP) {
        OutF[(size_t)row * 1024 + h * 128 + col] = v;
      } else if constexpr (MODE == MG1) {
        v += bias[col];
        v = fmaxf(v, 0.0f);
        OutB[(size_t)row * 1024 + col] = f2b(v);
      } else {  // MG2: + g2_b, sigmoid
        v += bias[col];
        v = 1.0f / (1.0f + __expf(-v));
        OutF[(size_t)row * 1024 + col] = v;
      }
    }
  }
}

// ---------------------------------------------------------------------------
// Fused per-c attention kernel: stage Fp[c] -> LDS bf16; scores = Qt·Fp^T
// (MFMA); softmax; P = attn·Fp (MFMA); also Et.mean for the gate input.
// LDS: Fp [64][1160] bf16 (pad 1152->1160: stride 2320B = 580 dw, 580%32=4
// -> frag reads land 2-way max = free), scores [8][64] f32.
// ---------------------------------------------------------------------------
__global__ __launch_bounds__(512) void attn_kern(
    const float* __restrict__ F, const float* __restrict__ Et,
    const unsigned short* __restrict__ Qtb,
    unsigned short* __restrict__ Pb, float* __restrict__ Etm)
{
  extern __shared__ char smem[];
  unsigned short* fp = (unsigned short*)smem;                       // [64][1160]
  float* sc = (float*)(smem + (size_t)64 * 1160 * 2);               // [8][64]

  const int c = blockIdx.x;
  const int tid = threadIdx.x;
  const int wv = tid >> 6, lane = tid & 63;
  const int l15 = lane & 15, s = lane >> 4;

  const float* Fc = F + (size_t)c * (64 * 1024);
  const float* Ec = Et + (size_t)c * (64 * 128);

  // ---- stage: Fp[c] = [F[c] | Et[c]] -> LDS bf16 ----
  #pragma unroll 4
  for (int j = 0; j < 36; ++j) {
    int i = tid + 512 * j;          // 0..18431, 288 float4 per row
    int row = i / 288;
    int c4 = (i % 288) * 4;
    float4 v;
    if (c4 < 1024) v = *(const float4*)(Fc + (size_t)row * 1024 + c4);
    else           v = *(const float4*)(Ec + (size_t)row * 128 + (c4 - 1024));
    u16x4 t4 = { f2b(v.x), f2b(v.y), f2b(v.z), f2b(v.w) };
    *(u16x4*)(fp + (size_t)row * 1160 + c4) = t4;
  }
  __syncthreads();

  // ---- scores (waves 0-3; N-tile = wave) + Et.mean (waves 4-7) ----
  if (wv < 4) {
    f32x4 acc = {};
    const unsigned short* qrow = Qtb + ((size_t)c * 8 + l15) * 1152 + s * 8;
    const unsigned short* frow = fp + (size_t)(wv * 16 + l15) * 1160 + s * 8;
    #pragma unroll 4
    for (int x0 = 0; x0 < 1152; x0 += 32) {
      bf16x8 aF = {};
      if (l15 < 8) aF = *(const bf16x8*)(qrow + x0);   // rows h>=8 masked to 0
      bf16x8 bF = *(const bf16x8*)(frow + x0);
      acc = __builtin_amdgcn_mfma_f32_16x16x32_bf16(aF, bF, acc, 0, 0, 0);
    }
    if (s < 2) {
      #pragma unroll
      for (int r = 0; r < 4; ++r)
        sc[(s * 4 + r) * 64 + wv * 16 + l15] = acc[r] * 0.08838834764831845f; // 1/sqrt(128)
    }
  } else {
    int u = tid - 256;
    if (u < 128) {   // Et.mean from global fp32 (L2-hot, exact)
      float ssum = 0.f;
      #pragma unroll 8
      for (int k = 0; k < 64; ++k) ssum += Ec[(size_t)k * 128 + u];
      Etm[(size_t)c * 128 + u] = ssum * (1.0f / 64.0f);
    }
  }
  __syncthreads();

  // ---- softmax: wave wv handles head h=wv, lane = kt ----
  {
    float sv = sc[wv * 64 + lane];
    float m = sv;
    #pragma unroll
    for (int off = 32; off; off >>= 1) m = fmaxf(m, __shfl_xor(m, off));
    float e = __expf(sv - m);
    float sum = e;
    #pragma unroll
    for (int off = 32; off; off >>= 1) sum += __shfl_xor(sum, off);
    sc[wv * 64 + lane] = e / sum;
  }
  __syncthreads();

  // ---- P = attn · Fp (M=8 pad 16, N=1152, K=64). kt-slot map f'(s,j)=j*4+s
  // (same bijection on both operands => correct contraction). ----
  bf16x8 pa[2];
  #pragma unroll
  for (int ki = 0; ki < 2; ++ki) {
    bf16x8 t = {};
    if (l15 < 8) {
      #pragma unroll
      for (int j = 0; j < 8; ++j)
        t[j] = (short)f2b(sc[l15 * 64 + ki * 32 + j * 4 + s]);
    }
    pa[ki] = t;
  }
  #pragma unroll
  for (int ntl = 0; ntl < 9; ++ntl) {
    int nt = wv * 9 + ntl;
    int x = nt * 16 + l15;
    f32x4 acc = {};
    #pragma unroll
    for (int ki = 0; ki < 2; ++ki) {
      bf16x8 bF;
      #pragma unroll
      for (int j = 0; j < 8; ++j)
        bF[j] = (short)fp[(size_t)(ki * 32 + j * 4 + s) * 1160 + x];
      acc = __builtin_amdgcn_mfma_f32_16x16x32_bf16(pa[ki], bF, acc, 0, 0, 0);
    }
    if (s < 2) {
      #pragma unroll
      for (int r = 0; r < 4; ++r) {
        int hh = s * 4 + r;
        Pb[((size_t)c * 8 + hh) * 1152 + x] = f2b(acc[r]);
      }
    }
  }
}

// ---------------------------------------------------------------------------
// Finalize: out = normalize(w + g*A) per row.
// ---------------------------------------------------------------------------
__global__ __launch_bounds__(256) void finalize_kern(
    const float* __restrict__ w, const float* __restrict__ A,
    const float* __restrict__ g, float* __restrict__ out)
{
  __shared__ float red[4];
  int c = blockIdx.x, t = threadIdx.x;
  int lane = t & 63, wid = t >> 6;
  size_t base = (size_t)c * 1024 + t * 4;
  float4 wv = *(const float4*)(w + base);
  float4 av = *(const float4*)(A + base);
  float4 gv = *(const float4*)(g + base);
  float4 o;
  o.x = wv.x + gv.x * av.x;
  o.y = wv.y + gv.y * av.y;
  o.z = wv.z + gv.z * av.z;
  o.w = wv.w + gv.w * av.w;
  float ss = o.x * o.x + o.y * o.y + o.z * o.z + o.w * o.w;
  #pragma unroll
  for (int off = 32; off; off >>= 1) ss += __shfl_xor(ss, off);
  if (lane == 0) red[wid] = ss;
  __syncthreads();
  float tot = red[0] + red[1] + red[2] + red[3];
  float inv = 1.0f / fmaxf(sqrtf(tot), 1e-12f);
  o.x *= inv; o.y *= inv; o.z *= inv; o.w *= inv;
  *(float4*)(out + base) = o;
}

// ---------------------------------------------------------------------------
extern "C" void kernel_launch(void* const* d_in, const int* in_sizes, int n_in,
                              void* d_out, int out_size, void* d_ws, size_t ws_size,
                              hipStream_t stream)
{
  (void)in_sizes; (void)n_in; (void)out_size; (void)ws_size;
  const float* w    = (const float*)d_in[0];
  const float* F    = (const float*)d_in[1];
  const float* Et   = (const float*)d_in[2];
  const float* fC   = (const float*)d_in[3];
  const float* W1   = (const float*)d_in[4];
  const float* W2   = (const float*)d_in[5];
  const float* Wv   = (const float*)d_in[6];
  const float* Wf   = (const float*)d_in[7];
  // d_in[8] = alpha: provably unused (constant-over-k shift of scores ->
  // softmax invariant; V gets no fC term).
  const float* beta = (const float*)d_in[9];
  const float* g1w  = (const float*)d_in[10];
  const float* g1b  = (const float*)d_in[11];
  const float* g2w  = (const float*)d_in[12];
  const float* g2b  = (const float*)d_in[13];
  float* outp = (float*)d_out;

  char* ws = (char*)d_ws;
  // layout (bytes):
  unsigned short* Qb  = (unsigned short*)(ws + 0);           // 2048x1024 bf16   (4 MB)
  unsigned short* Qtb = (unsigned short*)(ws + 4194304);     // 2048x8x1152 bf16 (36 MB)
  unsigned short* Pb  = (unsigned short*)(ws + 41943040);    // 2048x8x1152 bf16 (36 MB)
  float* Etm          = (float*)(ws + 79691776);             // 2048x128 f32     (1 MB)
  float* Afp          = (float*)(ws + 80740352);             // 2048x1024 f32    (8 MB)
  unsigned short* Hm  = (unsigned short*)(ws + 4194304);     // reuse Qtb (dead after attn)
  float* Gf           = (float*)(ws + 0);                    // reuse Qb  (dead after MQT)

  // 1) Q = w@W2^T + beta*(fC@Wf^T)  -> bf16
  gemm64<MQ><<<dim3(16, 32), 256, 0, stream>>>(w, fC, nullptr, W2, Wf, beta,
                                               nullptr, nullptr, Qb);
  // 2) Qt[c,h,:] = Qh[c,h,:]@W1[hslice,:]  -> bf16
  gemm64<MQT><<<dim3(18, 32, 8), 256, 0, stream>>>(nullptr, nullptr, Qb, W1,
                                                   nullptr, nullptr, nullptr,
                                                   nullptr, Qtb);
  // 3) fused attention core + Et.mean
  attn_kern<<<2048, 512, 150528, stream>>>(F, Et, Qtb, Pb, Etm);
  // 4) A[c,hslice] = P[c,h,:]@Wv[hslice,:]^T -> f32
  gemm64<MAP><<<dim3(2, 32, 8), 256, 0, stream>>>(nullptr, nullptr, Pb, Wv,
                                                  nullptr, nullptr, nullptr,
                                                  Afp, nullptr);
  // 5) hmid = relu([w|Etmean]@g1_w^T + g1_b) -> bf16
  gemm64<MG1><<<dim3(16, 32), 256, 0, stream>>>(w, Etm, nullptr, g1w, nullptr,
                                                nullptr, g1b, nullptr, Hm);
  // 6) g = sigmoid(hmid@g2_w^T + g2_b) -> f32
  gemm64<MG2><<<dim3(16, 32), 256, 0, stream>>>(nullptr, nullptr, Hm, g2w,
                                                nullptr, nullptr, g2b, Gf,
                                                nullptr);
  // 7) out = normalize(w + g*A)
  finalize_kern<<<2048, 256, 0, stream>>>(w, Afp, Gf, outp);
}

// Round 2
// 1116.105 us; speedup vs baseline: 1.1202x; 1.1202x over previous
//
#include <hip/hip_runtime.h>

// Problem constants
// C=2048, KT=64, D=1024, De=128, Df=256, H=8, dh=128, X=D+De=1152, PH=1024

#define DEV __device__ __forceinline__

typedef __attribute__((ext_vector_type(4))) float f32x4;
typedef __attribute__((ext_vector_type(8))) short bf16x8;
typedef __attribute__((ext_vector_type(4))) unsigned short u16x4;

DEV unsigned short f2b(float f) {
  unsigned int u = __builtin_bit_cast(unsigned int, f);
  u = u + 0x7fffu + ((u >> 16) & 1u);   // round-to-nearest-even
  return (unsigned short)(u >> 16);
}

DEV bf16x8 cvt8(f32x4 a, f32x4 b) {
  bf16x8 r;
  r[0] = (short)f2b(a[0]); r[1] = (short)f2b(a[1]);
  r[2] = (short)f2b(a[2]); r[3] = (short)f2b(a[3]);
  r[4] = (short)f2b(b[0]); r[5] = (short)f2b(b[1]);
  r[6] = (short)f2b(b[2]); r[7] = (short)f2b(b[3]);
  return r;
}

// async global->LDS, 16B per lane; LDS dest = uniform base + lane*16.
DEV void gll16(const void* g, void* l) {
  __builtin_amdgcn_global_load_lds(
      (const __attribute__((address_space(1))) void*)g,
      (__attribute__((address_space(3))) void*)l, 16, 0, 0);
}

#define SBAR0() __builtin_amdgcn_sched_barrier(0)
#define LGKM_BARRIER() do { \
    asm volatile("s_waitcnt lgkmcnt(0)" ::: "memory"); \
    SBAR0(); __builtin_amdgcn_s_barrier(); SBAR0(); } while (0)

// ---------------------------------------------------------------------------
// Generic 64x64-tile bf16 MFMA GEMM, K-step 64, XOR-swizzled LDS.
// ---------------------------------------------------------------------------
enum { MQ = 0, MQT = 1, MAP = 2, MG1 = 3, MG2 = 4 };

template <int MODE>
__global__ __launch_bounds__(256) void gemm64(
    const float* __restrict__ A1, const float* __restrict__ A2,
    const unsigned short* __restrict__ Ab,
    const float* __restrict__ B1, const float* __restrict__ B2,
    const float* __restrict__ scale2, const float* __restrict__ bias,
    float* __restrict__ OutF, unsigned short* __restrict__ OutB)
{
  __shared__ unsigned short As[64 * 64];  // [row][64 k], 16B-granule swizzled
  __shared__ unsigned short Bs[64 * 64];

  const int tid = threadIdx.x;
  const int lane = tid & 63, wv = tid >> 6;
  const int l15 = lane & 15, s = lane >> 4;
  const int bx = blockIdx.x, by = blockIdx.y, h = blockIdx.z;
  const int c0 = by * 64;
  const int n0 = bx * 64;

  int K;
  if constexpr (MODE == MQ) K = 1280;        // 1024 (w·W2) + 256 (beta·fC·Wf)
  else if constexpr (MODE == MQT) K = 128;
  else if constexpr (MODE == MAP) K = 1152;
  else if constexpr (MODE == MG1) K = 1152;  // 1024 (w) + 128 (Etmean)
  else K = 1024;

  float s2 = 1.0f;
  if constexpr (MODE == MQ) s2 = scale2[0];  // beta

  f32x4 acc[4] = {};

  for (int k0 = 0; k0 < K; k0 += 64) {
    // ---- stage A tile (64 rows x 64 k) ----
    if constexpr (MODE == MQ || MODE == MG1) {
      #pragma unroll
      for (int p = 0; p < 4; ++p) {
        int flat = tid + 256 * p;
        int r = flat >> 4, kc = (flat & 15) * 4;
        int k = k0 + kc;
        float4 v;
        if constexpr (MODE == MQ) {
          if (k < 1024) v = *(const float4*)(A1 + (size_t)(c0 + r) * 1024 + k);
          else {
            v = *(const float4*)(A2 + (size_t)(c0 + r) * 256 + (k - 1024));
            v.x *= s2; v.y *= s2; v.z *= s2; v.w *= s2;
          }
        } else {
          if (k < 1024) v = *(const float4*)(A1 + (size_t)(c0 + r) * 1024 + k);
          else v = *(const float4*)(A2 + (size_t)(c0 + r) * 128 + (k - 1024));
        }
        u16x4 t4 = { f2b(v.x), f2b(v.y), f2b(v.z), f2b(v.w) };
        *(u16x4*)((char*)As + r * 128 + ((kc * 2) ^ ((r & 7) << 4))) = t4;
      }
    } else {
      #pragma unroll
      for (int p = 0; p < 2; ++p) {
        int flat = tid + 256 * p;
        int r = flat >> 3, kc8 = (flat & 7) * 8;
        size_t lda, aoff;
        if constexpr (MODE == MQT)      { lda = 1024; aoff = (size_t)h * 128; }
        else if constexpr (MODE == MAP) { lda = 9216; aoff = (size_t)h * 1152; }
        else                            { lda = 1024; aoff = 0; }
        bf16x8 v = *(const bf16x8*)(Ab + (size_t)(c0 + r) * lda + aoff + k0 + kc8);
        *(bf16x8*)((char*)As + r * 128 + ((kc8 * 2) ^ ((r & 7) << 4))) = v;
      }
    }
    // ---- stage B tile ----
    if constexpr (MODE == MQT) {
      // W1 slice, contraction = row index: transpose into LDS
      #pragma unroll
      for (int p = 0; p < 16; ++p) {
        int flat = tid + 256 * p;
        int kk = flat >> 6, nn = flat & 63;
        float v = B1[(size_t)(h * 128 + k0 + kk) * 1152 + n0 + nn];
        *(unsigned short*)((char*)Bs + nn * 128 + ((kk * 2) ^ ((nn & 7) << 4))) = f2b(v);
      }
    } else {
      #pragma unroll
      for (int p = 0; p < 4; ++p) {
        int flat = tid + 256 * p;
        int nn = flat >> 4, kc = (flat & 15) * 4;
        int k = k0 + kc;
        float4 v;
        if constexpr (MODE == MQ) {
          if (k < 1024) v = *(const float4*)(B1 + (size_t)(n0 + nn) * 1024 + k);
          else v = *(const float4*)(B2 + (size_t)(n0 + nn) * 256 + (k - 1024));
        } else if constexpr (MODE == MAP) {
          v = *(const float4*)(B1 + (size_t)(h * 128 + n0 + nn) * 1152 + k);
        } else if constexpr (MODE == MG1) {
          v = *(const float4*)(B1 + (size_t)(n0 + nn) * 1152 + k);
        } else {  // MG2
          v = *(const float4*)(B1 + (size_t)(n0 + nn) * 1024 + k);
        }
        u16x4 t4 = { f2b(v.x), f2b(v.y), f2b(v.z), f2b(v.w) };
        *(u16x4*)((char*)Bs + nn * 128 + ((kc * 2) ^ ((nn & 7) << 4))) = t4;
      }
    }
    __syncthreads();
    // ---- fragments + MFMA (wave wv owns N-sub [wv*16, wv*16+16)) ----
    #pragma unroll
    for (int kk = 0; kk < 2; ++kk) {
      bf16x8 bF = *(const bf16x8*)((char*)Bs + (wv * 16 + l15) * 128 +
                                   ((kk * 64 + s * 16) ^ ((l15 & 7) << 4)));
      #pragma unroll
      for (int ms = 0; ms < 4; ++ms) {
        bf16x8 aF = *(const bf16x8*)((char*)As + (ms * 16 + l15) * 128 +
                                     ((kk * 64 + s * 16) ^ ((l15 & 7) << 4)));
        acc[ms] = __builtin_amdgcn_mfma_f32_16x16x32_bf16(aF, bF, acc[ms], 0, 0, 0);
      }
    }
    __syncthreads();
  }

  // ---- epilogue: D layout col=lane&15, row=(lane>>4)*4+reg ----
  #pragma unroll
  for (int ms = 0; ms < 4; ++ms) {
    #pragma unroll
    for (int r = 0; r < 4; ++r) {
      int row = c0 + ms * 16 + s * 4 + r;
      int col = n0 + wv * 16 + l15;
      float v = acc[ms][r];
      if constexpr (MODE == MQ) {
        OutB[(size_t)row * 1024 + col] = f2b(v);
      } else if constexpr (MODE == MQT) {
        OutB[(size_t)row * 9216 + h * 1152 + col] = f2b(v);
      } else if constexpr (MODE == MAP) {
        OutF[(size_t)row * 1024 + h * 128 + col] = v;
      } else if constexpr (MODE == MG1) {
        v += bias[col];
        v = fmaxf(v, 0.0f);
        OutB[(size_t)row * 1024 + col] = f2b(v);
      } else {  // MG2: + g2_b, sigmoid
        v += bias[col];
        v = 1.0f / (1.0f + __expf(-v));
        OutF[(size_t)row * 1024 + col] = v;
      }
    }
  }
}

// ---------------------------------------------------------------------------
// Flash-tiled attention: 4 kt-tiles of 16 rows, fp32 staged via
// global_load_lds (double-buffered, pre-swizzled source), online softmax,
// P accumulated in registers. Also emits Et.mean.
// LDS: Ft[2][16][1024]f32 (swz32B) | Et[2][16][128]f32 (swz32B) |
//      psc[8][256]f32 | wl[16][32]bf16 | state
// ---------------------------------------------------------------------------
#define FT_OFF 0
#define ET_OFF 131072
#define PSC_OFF 147456
#define WL_OFF 155648
#define ST_OFF 156672

DEV void stage_tile(const float* Fc, const float* Ec, char* FtBuf, char* EtBuf,
                    int t, int wv, int lane) {
  const int l16 = lane * 16;
  #pragma unroll
  for (int i = 0; i < 8; ++i) {
    int ci = wv * 8 + i;           // 64 chunks of 1KB: row r quarter q
    int r = ci >> 2, q = ci & 3;
    int swz = (r & 7) << 5;
    const char* src = (const char*)Fc + (size_t)(t * 16 + r) * 4096 + q * 1024 + (l16 ^ swz);
    gll16(src, FtBuf + ci * 1024);
  }
  {
    int r = 2 * wv + (lane >> 5);  // 1KB = 2 rows of 512B
    int b = (lane & 31) * 16;
    int swz = (r & 7) << 5;
    const char* src = (const char*)Ec + (size_t)(t * 16 + r) * 512 + (b ^ swz);
    gll16(src, EtBuf + wv * 1024);
  }
}

__global__ __launch_bounds__(512, 2) void attn_kern(
    const float* __restrict__ F, const float* __restrict__ Et,
    const unsigned short* __restrict__ Qtb,
    unsigned short* __restrict__ Pb, float* __restrict__ Etm)
{
  extern __shared__ char smem[];
  float* psc = (float*)(smem + PSC_OFF);            // [8 waves][256]
  unsigned short* wl = (unsigned short*)(smem + WL_OFF);  // [16][32] bf16, cols>=16 zero
  float* mrun = (float*)(smem + ST_OFF);            // [8]
  float* lrun = mrun + 8;
  float* rfs  = mrun + 16;

  const int c = blockIdx.x;
  const int tid = threadIdx.x;
  const int wv = tid >> 6, lane = tid & 63;
  const int l15 = lane & 15, s = lane >> 4;

  const float* Fc = F + (size_t)c * 65536;
  const float* Ec = Et + (size_t)c * 8192;

  // init flash state + zero-padded weight tile
  wl[tid] = 0;
  if (tid < 8) { mrun[tid] = -1e30f; lrun[tid] = 0.0f; rfs[tid] = 0.0f; }

  // prologue: stage tile 0
  stage_tile(Fc, Ec, smem + FT_OFF, smem + ET_OFF, 0, wv, lane);

  // scores K-split: waves 0-3 -> 160 (5 chunks), waves 4-7 -> 128 (4 chunks)
  const int nk  = (wv < 4) ? 5 : 4;
  const int xk0 = (wv < 4) ? wv * 160 : 640 + (wv - 4) * 128;
  bf16x8 qf[5];
  #pragma unroll
  for (int i = 0; i < 5; ++i) { bf16x8 z = {}; qf[i] = z; }
  if (l15 < 8) {
    const unsigned short* qp = Qtb + ((size_t)c * 8 + l15) * 1152 + xk0 + s * 8;
    #pragma unroll
    for (int i = 0; i < 5; ++i) if (i < nk) qf[i] = *(const bf16x8*)(qp + i * 32);
  }

  f32x4 pacc[9];
  #pragma unroll
  for (int i = 0; i < 9; ++i) { f32x4 z = {}; pacc[i] = z; }
  float etacc = 0.0f;

  for (int t = 0; t < 4; ++t) {
    char* Fcur = smem + FT_OFF + (t & 1) * 65536;
    char* Ecur = smem + ET_OFF + (t & 1) * 8192;

    // drains vmcnt: tile t ready for everyone
    __syncthreads();
    // issue next tile's loads; they fly during this tile's compute
    if (t < 3)
      stage_tile(Fc, Ec, smem + FT_OFF + ((t + 1) & 1) * 65536,
                 smem + ET_OFF + ((t + 1) & 1) * 8192, t + 1, wv, lane);
    SBAR0();

    // ---- scores: partial over this wave's x-chunk, rows=h(l15), col=kt(tile) ----
    {
      f32x4 sa = {};
      #pragma unroll
      for (int i = 0; i < 5; ++i) {
        if (i < nk) {
          int xk = xk0 + i * 32;
          const char* base; int off;
          if (xk < 1024) { base = Fcur; off = l15 * 4096 + ((xk * 4 + s * 32) ^ ((l15 & 7) << 5)); }
          else           { base = Ecur; off = l15 * 512  + (((xk - 1024) * 4 + s * 32) ^ ((l15 & 7) << 5)); }
          f32x4 u0 = *(const f32x4*)(base + off);
          f32x4 u1 = *(const f32x4*)(base + off + 16);
          sa = __builtin_amdgcn_mfma_f32_16x16x32_bf16(qf[i], cvt8(u0, u1), sa, 0, 0, 0);
        }
      }
      *(f32x4*)(psc + wv * 256 + l15 * 16 + s * 4) = sa;
    }
    LGKM_BARRIER();

    // ---- softmax update (waves 0-1) | Et.mean partial (waves 2-3) ----
    if (tid < 128) {
      int hh = tid >> 4, j = tid & 15;
      float sv = 0.0f;
      #pragma unroll
      for (int w2 = 0; w2 < 8; ++w2) sv += psc[w2 * 256 + j * 16 + hh];
      sv *= 0.08838834764831845f;   // 1/sqrt(128)
      float mt = sv;
      #pragma unroll
      for (int o = 8; o; o >>= 1) mt = fmaxf(mt, __shfl_xor(mt, o));
      float mo = mrun[hh];
      float mn = fmaxf(mo, mt);
      float e = __expf(sv - mn);
      float lt = e;
      #pragma unroll
      for (int o = 8; o; o >>= 1) lt += __shfl_xor(lt, o);
      float rf = __expf(mo - mn);
      wl[hh * 32 + j] = f2b(e);
      if (j == 0) { mrun[hh] = mn; lrun[hh] = lrun[hh] * rf + lt; rfs[hh] = rf; }
    } else if (tid < 256) {
      int u = tid - 128;
      float a = 0.0f;
      #pragma unroll
      for (int r = 0; r < 16; ++r)
        a += *(const float*)(Ecur + r * 512 + ((u * 4) ^ ((r & 7) << 5)));
      etacc += a;
    }
    LGKM_BARRIER();

    // ---- P += w·Fp_tile, x-split 8 waves x 9 chunks of 16 ----
    {
      bf16x8 pa0 = *(const bf16x8*)((const char*)wl + l15 * 64 + s * 16);
      float rfv[4];
      #pragma unroll
      for (int r = 0; r < 4; ++r) rfv[r] = rfs[(s * 4 + r) & 7];
      #pragma unroll
      for (int i = 0; i < 9; ++i) {
        #pragma unroll
        for (int r = 0; r < 4; ++r) pacc[i][r] *= rfv[r];
        int ch = wv * 9 + i;
        int xg = ch * 16 + l15;
        bf16x8 bf;
        #pragma unroll
        for (int j = 0; j < 8; ++j) {
          float v = 0.0f;
          if (s < 2) {
            int k = s * 8 + j;
            if (ch < 64) v = *(const float*)(Fcur + k * 4096 + ((xg * 4) ^ ((k & 7) << 5)));
            else         v = *(const float*)(Ecur + k * 512  + (((xg - 1024) * 4) ^ ((k & 7) << 5)));
          }
          bf[j] = (short)f2b(v);
        }
        pacc[i] = __builtin_amdgcn_mfma_f32_16x16x32_bf16(pa0, bf, pacc[i], 0, 0, 0);
      }
    }
    SBAR0();
  }

  // ---- finalize: P/l -> bf16 Pb; Et.mean ----
  float rl[4];
  #pragma unroll
  for (int r = 0; r < 4; ++r) rl[r] = 1.0f / lrun[(s * 4 + r) & 7];
  if (s < 2) {
    #pragma unroll
    for (int i = 0; i < 9; ++i) {
      int xg = (wv * 9 + i) * 16 + l15;
      #pragma unroll
      for (int r = 0; r < 4; ++r) {
        int hh = s * 4 + r;
        Pb[((size_t)c * 8 + hh) * 1152 + xg] = f2b(pacc[i][r] * rl[r]);
      }
    }
  }
  if (tid >= 128 && tid < 256)
    Etm[(size_t)c * 128 + (tid - 128)] = etacc * (1.0f / 64.0f);
}

// ---------------------------------------------------------------------------
// Finalize: out = normalize(w + g*A) per row.
// ---------------------------------------------------------------------------
__global__ __launch_bounds__(256) void finalize_kern(
    const float* __restrict__ w, const float* __restrict__ A,
    const float* __restrict__ g, float* __restrict__ out)
{
  __shared__ float red[4];
  int c = blockIdx.x, t = threadIdx.x;
  int lane = t & 63, wid = t >> 6;
  size_t base = (size_t)c * 1024 + t * 4;
  float4 wv = *(const float4*)(w + base);
  float4 av = *(const float4*)(A + base);
  float4 gv = *(const float4*)(g + base);
  float4 o;
  o.x = wv.x + gv.x * av.x;
  o.y = wv.y + gv.y * av.y;
  o.z = wv.z + gv.z * av.z;
  o.w = wv.w + gv.w * av.w;
  float ss = o.x * o.x + o.y * o.y + o.z * o.z + o.w * o.w;
  #pragma unroll
  for (int off = 32; off; off >>= 1) ss += __shfl_xor(ss, off);
  if (lane == 0) red[wid] = ss;
  __syncthreads();
  float tot = red[0] + red[1] + red[2] + red[3];
  float inv = 1.0f / fmaxf(sqrtf(tot), 1e-12f);
  o.x *= inv; o.y *= inv; o.z *= inv; o.w *= inv;
  *(float4*)(out + base) = o;
}

// ---------------------------------------------------------------------------
extern "C" void kernel_launch(void* const* d_in, const int* in_sizes, int n_in,
                              void* d_out, int out_size, void* d_ws, size_t ws_size,
                              hipStream_t stream)
{
  (void)in_sizes; (void)n_in; (void)out_size; (void)ws_size;
  const float* w    = (const float*)d_in[0];
  const float* F    = (const float*)d_in[1];
  const float* Et   = (const float*)d_in[2];
  const float* fC   = (const float*)d_in[3];
  const float* W1   = (const float*)d_in[4];
  const float* W2   = (const float*)d_in[5];
  const float* Wv   = (const float*)d_in[6];
  const float* Wf   = (const float*)d_in[7];
  // d_in[8] = alpha: provably unused (constant-over-k shift of scores ->
  // softmax invariant; V gets no fC term).
  const float* beta = (const float*)d_in[9];
  const float* g1w  = (const float*)d_in[10];
  const float* g1b  = (const float*)d_in[11];
  const float* g2w  = (const float*)d_in[12];
  const float* g2b  = (const float*)d_in[13];
  float* outp = (float*)d_out;

  char* ws = (char*)d_ws;
  unsigned short* Qb  = (unsigned short*)(ws + 0);           // 2048x1024 bf16   (4 MB)
  unsigned short* Qtb = (unsigned short*)(ws + 4194304);     // 2048x8x1152 bf16 (36 MB)
  unsigned short* Pb  = (unsigned short*)(ws + 41943040);    // 2048x8x1152 bf16 (36 MB)
  float* Etm          = (float*)(ws + 79691776);             // 2048x128 f32     (1 MB)
  float* Afp          = (float*)(ws + 80740352);             // 2048x1024 f32    (8 MB)
  unsigned short* Hm  = (unsigned short*)(ws + 4194304);     // reuse Qtb (dead after attn)
  float* Gf           = (float*)(ws + 0);                    // reuse Qb  (dead after MQT)

  // 1) Q = w@W2^T + beta*(fC@Wf^T)  -> bf16
  gemm64<MQ><<<dim3(16, 32), 256, 0, stream>>>(w, fC, nullptr, W2, Wf, beta,
                                               nullptr, nullptr, Qb);
  // 2) Qt[c,h,:] = Qh[c,h,:]@W1[hslice,:]  -> bf16
  gemm64<MQT><<<dim3(18, 32, 8), 256, 0, stream>>>(nullptr, nullptr, Qb, W1,
                                                   nullptr, nullptr, nullptr,
                                                   nullptr, Qtb);
  // 3) fused flash attention core + Et.mean
  attn_kern<<<2048, 512, 156800, stream>>>(F, Et, Qtb, Pb, Etm);
  // 4) A[c,hslice] = P[c,h,:]@Wv[hslice,:]^T -> f32
  gemm64<MAP><<<dim3(2, 32, 8), 256, 0, stream>>>(nullptr, nullptr, Pb, Wv,
                                                  nullptr, nullptr, nullptr,
                                                  Afp, nullptr);
  // 5) hmid = relu([w|Etmean]@g1_w^T + g1_b) -> bf16
  gemm64<MG1><<<dim3(16, 32), 256, 0, stream>>>(w, Etm, nullptr, g1w, nullptr,
                                                nullptr, g1b, nullptr, Hm);
  // 6) g = sigmoid(hmid@g2_w^T + g2_b) -> f32
  gemm64<MG2><<<dim3(16, 32), 256, 0, stream>>>(nullptr, nullptr, Hm, g2w,
                                                nullptr, nullptr, g2b, Gf,
                                                nullptr);
  // 7) out = normalize(w + g*A)
  finalize_kern<<<2048, 256, 0, stream>>>(w, Afp, Gf, outp);
}